// Round 1
// baseline (10560.831 us; speedup 1.0000x reference)
//
#include <hip/hip_runtime.h>
#include <math.h>

#define BSZ 512
#define TT  100
#define NDD 10
#define DSS 6
#define INS 256
#define HID 256
#define CAT 2816   // INS*NDD + HID
#define KZ  320    // 64 (desc: 60 + 4 pad) + 256 (h)
#define NOUT 266   // 256 (W2 rows) + 10 (Wv rows)
#define SPLITK 8
#define KCH 352    // 2816 / 8

__device__ __forceinline__ float sigf(float x) { return 1.0f / (1.0f + expf(-x)); }
__device__ __forceinline__ float dot4(float4 a, float4 b) {
    return a.x*b.x + a.y*b.y + a.z*b.z + a.w*b.w;
}

// ---------------------------------------------------------------------------
// Precompute: Wzc[j][0:60] = fold(W1, Wd); [60:64]=0; [64:320] = W1[j, 2560:2816]
// bfold[j] = b1[j] + sum_{n,i} W1[j, n*256+i] * bd[i]
// ---------------------------------------------------------------------------
__global__ __launch_bounds__(64) void k_fold(
    const float* __restrict__ W1, const float* __restrict__ Wd,
    const float* __restrict__ bd, const float* __restrict__ b1,
    float* __restrict__ Wzc, float* __restrict__ bfold)
{
    __shared__ float sW1[2560];
    __shared__ float sWd[INS * DSS];
    __shared__ float red[64];
    const int j = blockIdx.x;
    const int tid = threadIdx.x;
    for (int f = tid; f < INS * DSS; f += 64) sWd[f] = Wd[f];
    for (int f = tid; f < 2560; f += 64) sW1[f] = W1[(size_t)j * CAT + f];
    __syncthreads();
    if (tid < 60) {
        int n = tid / DSS, d = tid - n * DSS;
        float acc = 0.f;
        for (int i = 0; i < INS; ++i) acc += sW1[n * INS + i] * sWd[i * DSS + d];
        Wzc[j * KZ + tid] = acc;
    } else {
        Wzc[j * KZ + tid] = 0.f;  // tid 60..63 pad
    }
    for (int q = tid; q < HID; q += 64)
        Wzc[j * KZ + 64 + q] = W1[(size_t)j * CAT + 2560 + q];
    float acc = 0.f;
    for (int p = tid; p < 2560; p += 64) acc += sW1[p] * bd[p & (INS - 1)];
    red[tid] = acc;
    __syncthreads();
    for (int s = 32; s > 0; s >>= 1) {
        if (tid < s) red[tid] += red[tid + s];
        __syncthreads();
    }
    if (tid == 0) bfold[j] = b1[j] + red[0];
}

// ---------------------------------------------------------------------------
// Precompute: Dfold[t][b][p] = desc[b][t][:,:] flattened (p<60), 0 for p in 60..63
// ---------------------------------------------------------------------------
__global__ __launch_bounds__(256) void k_dfold(
    const float* __restrict__ desc, float* __restrict__ Dfold)
{
    int idx = blockIdx.x * 256 + threadIdx.x;
    const int total = TT * BSZ * 64;
    if (idx >= total) return;
    int p = idx & 63;
    int tb = idx >> 6;           // t*BSZ + b
    int t = tb / BSZ;
    int b = tb - t * BSZ;
    Dfold[idx] = (p < 60) ? desc[(size_t)b * (TT * 60) + t * 60 + p] : 0.f;
}

// ---------------------------------------------------------------------------
// Per-step: gates GEMM (K=512 over [inp|h]) + fused LSTM cell.
// Writes h (double-buffered), c in-place, and xz[:, 64:320] = h_new.
// Blocks with blockIdx.y==0 also copy the step's Dfold slice into xz[:, 0:64].
// ---------------------------------------------------------------------------
__global__ __launch_bounds__(256) void k_gatecell(
    const float* __restrict__ inp, const float* __restrict__ hR,
    float* __restrict__ hW, float* __restrict__ c,
    float* __restrict__ xz, const float* __restrict__ Dfold_t,
    const float* __restrict__ Wih, const float* __restrict__ Whh,
    const float* __restrict__ bih, const float* __restrict__ bhh)
{
    __shared__ float sx[16][516];
    const int tid = threadIdx.x;
    const int b0 = blockIdx.x * 16;
    const int j0 = blockIdx.y * 16;
    for (int f = tid; f < 16 * 512; f += 256) {
        int bb = f >> 9, k = f & 511;
        sx[bb][k] = (k < 256) ? inp[(b0 + bb) * HID + k]
                              : hR[(b0 + bb) * HID + (k - 256)];
    }
    if (blockIdx.y == 0) {
        for (int f = tid; f < 16 * 64; f += 256) {
            int bb = f >> 6, p = f & 63;
            xz[(b0 + bb) * KZ + p] = Dfold_t[(b0 + bb) * 64 + p];
        }
    }
    __syncthreads();
    const int bb = tid & 15, jj = tid >> 4;
    const int j = j0 + jj;
    float ai = 0.f, af = 0.f, ag = 0.f, ao = 0.f;
    for (int k = 0; k < 256; k += 4) {
        float4 x = *(const float4*)&sx[bb][k];
        float4 w0 = *(const float4*)&Wih[(size_t)(j      ) * INS + k];
        float4 w1 = *(const float4*)&Wih[(size_t)(j + 256) * INS + k];
        float4 w2 = *(const float4*)&Wih[(size_t)(j + 512) * INS + k];
        float4 w3 = *(const float4*)&Wih[(size_t)(j + 768) * INS + k];
        ai += dot4(x, w0); af += dot4(x, w1); ag += dot4(x, w2); ao += dot4(x, w3);
    }
    for (int k = 0; k < 256; k += 4) {
        float4 x = *(const float4*)&sx[bb][256 + k];
        float4 w0 = *(const float4*)&Whh[(size_t)(j      ) * HID + k];
        float4 w1 = *(const float4*)&Whh[(size_t)(j + 256) * HID + k];
        float4 w2 = *(const float4*)&Whh[(size_t)(j + 512) * HID + k];
        float4 w3 = *(const float4*)&Whh[(size_t)(j + 768) * HID + k];
        ai += dot4(x, w0); af += dot4(x, w1); ag += dot4(x, w2); ao += dot4(x, w3);
    }
    ai += bih[j] + bhh[j];
    af += bih[j + 256] + bhh[j + 256];
    ag += bih[j + 512] + bhh[j + 512];
    ao += bih[j + 768] + bhh[j + 768];
    float ig = sigf(ai), fg = sigf(af), gg = tanhf(ag), og = sigf(ao);
    int bi = (b0 + bb) * HID + j;
    float cc = fg * c[bi] + ig * gg;
    c[bi] = cc;
    float hh = og * tanhf(cc);
    hW[bi] = hh;
    xz[(b0 + bb) * KZ + 64 + j] = hh;
}

// ---------------------------------------------------------------------------
// z = relu(xz @ Wzc.T + bfold)   M=512, N=2816, K=320
// ---------------------------------------------------------------------------
__global__ __launch_bounds__(256) void k_gemm_z(
    const float* __restrict__ A, const float* __restrict__ W,
    const float* __restrict__ bias, float* __restrict__ C)
{
    __shared__ float As[32][68];
    __shared__ float Ws[32][68];
    const int tid = threadIdx.x;
    const int m0 = blockIdx.x * 64;
    const int n0 = blockIdx.y * 64;
    const int tm = tid >> 4, tn = tid & 15;
    float4 acc0 = {0, 0, 0, 0}, acc1 = {0, 0, 0, 0}, acc2 = {0, 0, 0, 0}, acc3 = {0, 0, 0, 0};
    for (int kc = 0; kc < KZ; kc += 32) {
        for (int l = tid; l < 512; l += 256) {
            int m = l >> 3, q = l & 7;
            float4 v = *(const float4*)&A[(size_t)(m0 + m) * KZ + kc + q * 4];
            As[q * 4 + 0][m] = v.x; As[q * 4 + 1][m] = v.y;
            As[q * 4 + 2][m] = v.z; As[q * 4 + 3][m] = v.w;
        }
        for (int l = tid; l < 512; l += 256) {
            int n = l >> 3, q = l & 7;
            float4 v = *(const float4*)&W[(size_t)(n0 + n) * KZ + kc + q * 4];
            Ws[q * 4 + 0][n] = v.x; Ws[q * 4 + 1][n] = v.y;
            Ws[q * 4 + 2][n] = v.z; Ws[q * 4 + 3][n] = v.w;
        }
        __syncthreads();
        #pragma unroll
        for (int k = 0; k < 32; ++k) {
            float4 a = *(const float4*)&As[k][tm * 4];
            float4 b = *(const float4*)&Ws[k][tn * 4];
            acc0.x += a.x * b.x; acc0.y += a.x * b.y; acc0.z += a.x * b.z; acc0.w += a.x * b.w;
            acc1.x += a.y * b.x; acc1.y += a.y * b.y; acc1.z += a.y * b.z; acc1.w += a.y * b.w;
            acc2.x += a.z * b.x; acc2.y += a.z * b.y; acc2.z += a.z * b.z; acc2.w += a.z * b.w;
            acc3.x += a.w * b.x; acc3.y += a.w * b.y; acc3.z += a.w * b.z; acc3.w += a.w * b.w;
        }
        __syncthreads();
    }
    float4 b4 = *(const float4*)&bias[n0 + tn * 4];
    float4 accs[4] = {acc0, acc1, acc2, acc3};
    #pragma unroll
    for (int i = 0; i < 4; ++i) {
        float4 v;
        v.x = fmaxf(accs[i].x + b4.x, 0.f);
        v.y = fmaxf(accs[i].y + b4.y, 0.f);
        v.z = fmaxf(accs[i].z + b4.z, 0.f);
        v.w = fmaxf(accs[i].w + b4.w, 0.f);
        *(float4*)&C[(size_t)(m0 + tm * 4 + i) * CAT + n0 + tn * 4] = v;
    }
}

// ---------------------------------------------------------------------------
// Split-K partials of z @ [W2;Wv].T   M=512, N=266, K-chunk=352 per split
// ---------------------------------------------------------------------------
__global__ __launch_bounds__(256) void k_out_part(
    const float* __restrict__ Z, const float* __restrict__ W2,
    const float* __restrict__ Wv, float* __restrict__ part)
{
    __shared__ float As[32][68];
    __shared__ float Ws[32][68];
    const int tid = threadIdx.x;
    const int m0 = blockIdx.x * 64;
    const int n0 = blockIdx.y * 64;
    const int s  = blockIdx.z;
    const int k0 = s * KCH;
    const int tm = tid >> 4, tn = tid & 15;
    float4 acc0 = {0, 0, 0, 0}, acc1 = {0, 0, 0, 0}, acc2 = {0, 0, 0, 0}, acc3 = {0, 0, 0, 0};
    for (int kc = k0; kc < k0 + KCH; kc += 32) {
        for (int l = tid; l < 512; l += 256) {
            int m = l >> 3, q = l & 7;
            float4 v = *(const float4*)&Z[(size_t)(m0 + m) * CAT + kc + q * 4];
            As[q * 4 + 0][m] = v.x; As[q * 4 + 1][m] = v.y;
            As[q * 4 + 2][m] = v.z; As[q * 4 + 3][m] = v.w;
        }
        for (int l = tid; l < 512; l += 256) {
            int n = l >> 3, q = l & 7;
            int r = n0 + n;
            float4 v = {0, 0, 0, 0};
            if (r < 256)      v = *(const float4*)&W2[(size_t)r * CAT + kc + q * 4];
            else if (r < NOUT) v = *(const float4*)&Wv[(size_t)(r - 256) * CAT + kc + q * 4];
            Ws[q * 4 + 0][n] = v.x; Ws[q * 4 + 1][n] = v.y;
            Ws[q * 4 + 2][n] = v.z; Ws[q * 4 + 3][n] = v.w;
        }
        __syncthreads();
        #pragma unroll
        for (int k = 0; k < 32; ++k) {
            float4 a = *(const float4*)&As[k][tm * 4];
            float4 b = *(const float4*)&Ws[k][tn * 4];
            acc0.x += a.x * b.x; acc0.y += a.x * b.y; acc0.z += a.x * b.z; acc0.w += a.x * b.w;
            acc1.x += a.y * b.x; acc1.y += a.y * b.y; acc1.z += a.y * b.z; acc1.w += a.y * b.w;
            acc2.x += a.z * b.x; acc2.y += a.z * b.y; acc2.z += a.z * b.z; acc2.w += a.z * b.w;
            acc3.x += a.w * b.x; acc3.y += a.w * b.y; acc3.z += a.w * b.z; acc3.w += a.w * b.w;
        }
        __syncthreads();
    }
    float accs[4][4] = {
        {acc0.x, acc0.y, acc0.z, acc0.w}, {acc1.x, acc1.y, acc1.z, acc1.w},
        {acc2.x, acc2.y, acc2.z, acc2.w}, {acc3.x, acc3.y, acc3.z, acc3.w}};
    #pragma unroll
    for (int i = 0; i < 4; ++i) {
        int m = m0 + tm * 4 + i;
        #pragma unroll
        for (int jl = 0; jl < 4; ++jl) {
            int r = n0 + tn * 4 + jl;
            if (r < NOUT) part[((size_t)s * BSZ + m) * NOUT + r] = accs[i][jl];
        }
    }
}

// ---------------------------------------------------------------------------
// Reduce split-K partials; relu -> inp (next-step LSTM input), sigmoid -> out
// ---------------------------------------------------------------------------
__global__ __launch_bounds__(256) void k_fin(
    const float* __restrict__ part, const float* __restrict__ b2,
    const float* __restrict__ bv, float* __restrict__ inp,
    float* __restrict__ out, int t)
{
    int idx = blockIdx.x * 256 + threadIdx.x;
    if (idx >= BSZ * NOUT) return;
    int b = idx / NOUT;
    int r = idx - b * NOUT;
    float sv = 0.f;
    #pragma unroll
    for (int s = 0; s < SPLITK; ++s) sv += part[((size_t)s * BSZ + b) * NOUT + r];
    if (r < 256) {
        inp[b * HID + r] = fmaxf(sv + b2[r], 0.f);
    } else {
        int n = r - 256;
        out[(size_t)b * (TT * NDD) + t * NDD + n] = sigf(sv + bv[n]);
    }
}

// ---------------------------------------------------------------------------
extern "C" void kernel_launch(void* const* d_in, const int* in_sizes, int n_in,
                              void* d_out, int out_size, void* d_ws, size_t ws_size,
                              hipStream_t stream)
{
    const float* desc = (const float*)d_in[0];
    const float* Wd   = (const float*)d_in[1];
    const float* bd   = (const float*)d_in[2];
    const float* W1   = (const float*)d_in[3];
    const float* b1   = (const float*)d_in[4];
    const float* W2   = (const float*)d_in[5];
    const float* b2   = (const float*)d_in[6];
    const float* Wv   = (const float*)d_in[7];
    const float* bv   = (const float*)d_in[8];
    const float* Wih  = (const float*)d_in[9];
    const float* Whh  = (const float*)d_in[10];
    const float* bih  = (const float*)d_in[11];
    const float* bhh  = (const float*)d_in[12];
    float* out = (float*)d_out;
    float* ws  = (float*)d_ws;

    size_t off = 0;
    float* hA    = ws + off; off += BSZ * HID;
    float* hB    = ws + off; off += BSZ * HID;
    float* c     = ws + off; off += BSZ * HID;
    float* inp   = ws + off; off += BSZ * HID;
    float* xz    = ws + off; off += BSZ * KZ;
    float* z     = ws + off; off += (size_t)BSZ * CAT;
    float* Wzc   = ws + off; off += (size_t)CAT * KZ;
    float* bfold = ws + off; off += CAT;
    float* Dfold = ws + off; off += (size_t)TT * BSZ * 64;
    float* part  = ws + off; off += (size_t)SPLITK * BSZ * NOUT;

    hipMemsetAsync(hA,  0, BSZ * HID * sizeof(float), stream);
    hipMemsetAsync(c,   0, BSZ * HID * sizeof(float), stream);
    hipMemsetAsync(inp, 0, BSZ * HID * sizeof(float), stream);

    k_fold<<<CAT, 64, 0, stream>>>(W1, Wd, bd, b1, Wzc, bfold);
    k_dfold<<<(TT * BSZ * 64) / 256, 256, 0, stream>>>(desc, Dfold);

    for (int t = 0; t < TT; ++t) {
        const float* hR = (t & 1) ? hB : hA;
        float*       hWp = (t & 1) ? hA : hB;
        k_gatecell<<<dim3(32, 16), 256, 0, stream>>>(
            inp, hR, hWp, c, xz, Dfold + (size_t)t * BSZ * 64, Wih, Whh, bih, bhh);
        k_gemm_z<<<dim3(8, 44), 256, 0, stream>>>(xz, Wzc, bfold, z);
        k_out_part<<<dim3(8, 5, SPLITK), 256, 0, stream>>>(z, W2, Wv, part);
        k_fin<<<(BSZ * NOUT + 255) / 256, 256, 0, stream>>>(part, b2, bv, inp, out, t);
    }
}

// Round 2
// 4281.002 us; speedup vs baseline: 2.4669x; 2.4669x over previous
//
#include <hip/hip_runtime.h>
#include <math.h>

#define BSZ 512
#define TT  100
#define NDD 10
#define DSS 6
#define INS 256
#define HID 256
#define CAT 2816   // INS*NDD + HID
#define KZ  320    // 64 (desc: 60 + 4 pad) + 256 (h)
#define NOUTP 320  // padded output rows: 256 (W2) + 10 (Wv) + 54 zero
#define NOUT 266
#define SPLITK 8
#define KCH 352    // 2816 / 8

typedef short sh8 __attribute__((ext_vector_type(8)));
typedef float f4  __attribute__((ext_vector_type(4)));
typedef unsigned short ushort_t;

__device__ __forceinline__ float sigf(float x) { return 1.0f / (1.0f + expf(-x)); }

__device__ __forceinline__ ushort_t f2bf(float f) {
    union { float f; unsigned int u; } v; v.f = f;
    unsigned int r = (v.u + 0x7FFFu + ((v.u >> 16) & 1u)) >> 16;
    return (ushort_t)r;
}

// ---------------------------------------------------------------------------
// Precompute: Wzc[j][0:60] = fold(W1, Wd) (bf16); [60:64]=0; [64:320]=W1[j,2560:2816]
// bfold[j] = b1[j] + sum W1[j, n*256+i]*bd[i]   (fp32)
// ---------------------------------------------------------------------------
__global__ __launch_bounds__(64) void k_fold(
    const float* __restrict__ W1, const float* __restrict__ Wd,
    const float* __restrict__ bd, const float* __restrict__ b1,
    ushort_t* __restrict__ Wzc, float* __restrict__ bfold)
{
    __shared__ float sW1[2560];
    __shared__ float sWd[INS * DSS];
    __shared__ float red[64];
    const int j = blockIdx.x;
    const int tid = threadIdx.x;
    for (int f = tid; f < INS * DSS; f += 64) sWd[f] = Wd[f];
    for (int f = tid; f < 2560; f += 64) sW1[f] = W1[(size_t)j * CAT + f];
    __syncthreads();
    if (tid < 60) {
        int n = tid / DSS, d = tid - n * DSS;
        float acc = 0.f;
        for (int i = 0; i < INS; ++i) acc += sW1[n * INS + i] * sWd[i * DSS + d];
        Wzc[j * KZ + tid] = f2bf(acc);
    } else {
        Wzc[j * KZ + tid] = 0;  // pad 60..63
    }
    for (int q = tid; q < HID; q += 64)
        Wzc[j * KZ + 64 + q] = f2bf(W1[(size_t)j * CAT + 2560 + q]);
    float acc = 0.f;
    for (int p = tid; p < 2560; p += 64) acc += sW1[p] * bd[p & (INS - 1)];
    red[tid] = acc;
    __syncthreads();
    for (int s = 32; s > 0; s >>= 1) {
        if (tid < s) red[tid] += red[tid + s];
        __syncthreads();
    }
    if (tid == 0) bfold[j] = b1[j] + red[0];
}

// ---------------------------------------------------------------------------
// Dfold[t][b][p] = bf16(desc flattened), 0 for p in 60..63
// ---------------------------------------------------------------------------
__global__ __launch_bounds__(256) void k_dfold(
    const float* __restrict__ desc, ushort_t* __restrict__ Dfold)
{
    int idx = blockIdx.x * 256 + threadIdx.x;
    int p = idx & 63;
    int tb = idx >> 6;
    int t = tb / BSZ;
    int b = tb - t * BSZ;
    float v = (p < 60) ? desc[(size_t)b * (TT * 60) + t * 60 + p] : 0.f;
    Dfold[idx] = f2bf(v);
}

// ---------------------------------------------------------------------------
// Wg[newr=4j+g][0:256]=Wih[g*256+j], [256:512]=Whh[g*256+j]  (bf16)
// bg[newr] = bih[g*256+j] + bhh[g*256+j]
// ---------------------------------------------------------------------------
__global__ __launch_bounds__(256) void k_prep_g(
    const float* __restrict__ Wih, const float* __restrict__ Whh,
    const float* __restrict__ bih, const float* __restrict__ bhh,
    ushort_t* __restrict__ Wg, float* __restrict__ bg)
{
    int idx = blockIdx.x * 256 + threadIdx.x;   // 1024*512
    int newr = idx >> 9, k = idx & 511;
    int j = newr >> 2, g = newr & 3;
    int src_row = g * 256 + j;
    float v = (k < 256) ? Wih[(size_t)src_row * INS + k]
                        : Whh[(size_t)src_row * HID + (k - 256)];
    Wg[idx] = f2bf(v);
    if (k == 0) bg[newr] = bih[src_row] + bhh[src_row];
}

// ---------------------------------------------------------------------------
// Wout[r][k]: r<256 -> W2[r], r<266 -> Wv[r-256], else 0  (bf16)
// ---------------------------------------------------------------------------
__global__ __launch_bounds__(256) void k_prep_o(
    const float* __restrict__ W2, const float* __restrict__ Wv,
    ushort_t* __restrict__ Wout)
{
    int idx = blockIdx.x * 256 + threadIdx.x;   // 320*2816
    int r = idx / CAT, k = idx - r * CAT;
    float v = 0.f;
    if (r < 256) v = W2[(size_t)r * CAT + k];
    else if (r < NOUT) v = Wv[(size_t)(r - 256) * CAT + k];
    Wout[idx] = f2bf(v);
}

// ---------------------------------------------------------------------------
// Gates MFMA GEMM (M=512,N=1024,K=512) + fused LSTM cell.
// tile 64x64, 4 waves of 32x32. Reads xh (bf16 [512][512]), writes c (fp32),
// h -> xh_nxt[.,256:512] and xz[.,64:320] (bf16). by==0 blocks copy Dfold->xz[.,0:64].
// ---------------------------------------------------------------------------
__global__ __launch_bounds__(256) void k_gatecell(
    const ushort_t* __restrict__ xh, ushort_t* __restrict__ xh_nxt,
    float* __restrict__ c, ushort_t* __restrict__ xz,
    const ushort_t* __restrict__ Dt,
    const ushort_t* __restrict__ Wg, const float* __restrict__ bg)
{
    __shared__ float sg[64][65];
    const int tid = threadIdx.x;
    const int w = tid >> 6, l = tid & 63, quad = l >> 4, lr = l & 15;
    const int bx = blockIdx.x, by = blockIdx.y;

    if (by == 0) {
        for (int f = tid; f < 64 * 64; f += 256) {
            int bb = f >> 6, p = f & 63;
            xz[(bx * 64 + bb) * KZ + p] = Dt[(bx * 64 + bb) * 64 + p];
        }
    }

    const int m0 = bx * 64 + (w & 1) * 32;
    const int n0 = by * 64 + (w >> 1) * 32;
    f4 acc[2][2] = {};
    for (int kc = 0; kc < 512; kc += 32) {
        sh8 a[2], b[2];
        #pragma unroll
        for (int i = 0; i < 2; ++i)
            a[i] = *(const sh8*)&xh[(size_t)(m0 + i * 16 + lr) * 512 + kc + quad * 8];
        #pragma unroll
        for (int j = 0; j < 2; ++j)
            b[j] = *(const sh8*)&Wg[(size_t)(n0 + j * 16 + lr) * 512 + kc + quad * 8];
        #pragma unroll
        for (int i = 0; i < 2; ++i)
            #pragma unroll
            for (int j = 0; j < 2; ++j)
                acc[i][j] = __builtin_amdgcn_mfma_f32_16x16x32_bf16(a[i], b[j], acc[i][j], 0, 0, 0);
    }
    #pragma unroll
    for (int i = 0; i < 2; ++i)
        #pragma unroll
        for (int j = 0; j < 2; ++j)
            #pragma unroll
            for (int r = 0; r < 4; ++r)
                sg[(w & 1) * 32 + i * 16 + quad * 4 + r][(w >> 1) * 32 + j * 16 + lr] = acc[i][j][r];
    __syncthreads();

    #pragma unroll
    for (int p = 0; p < 4; ++p) {
        int idx = tid + p * 256;          // 1024 (b,j) pairs
        int bb = idx >> 4, jj = idx & 15;
        int bglob = bx * 64 + bb;
        int jglob = by * 16 + jj;
        float ai = sg[bb][4 * jj + 0] + bg[by * 64 + 4 * jj + 0];
        float af = sg[bb][4 * jj + 1] + bg[by * 64 + 4 * jj + 1];
        float ag = sg[bb][4 * jj + 2] + bg[by * 64 + 4 * jj + 2];
        float ao = sg[bb][4 * jj + 3] + bg[by * 64 + 4 * jj + 3];
        int ci = bglob * HID + jglob;
        float cc = sigf(af) * c[ci] + sigf(ai) * tanhf(ag);
        c[ci] = cc;
        float hh = sigf(ao) * tanhf(cc);
        ushort_t hb = f2bf(hh);
        xh_nxt[(size_t)bglob * 512 + 256 + jglob] = hb;
        xz[(size_t)bglob * KZ + 64 + jglob] = hb;
    }
}

// ---------------------------------------------------------------------------
// z = relu(xz @ Wzc.T + bfold)  M=512,N=2816,K=320. tile 64x64, waves 32x32.
// ---------------------------------------------------------------------------
__global__ __launch_bounds__(256) void k_gemm_z(
    const ushort_t* __restrict__ A, const ushort_t* __restrict__ W,
    const float* __restrict__ bias, ushort_t* __restrict__ z)
{
    const int tid = threadIdx.x;
    const int w = tid >> 6, l = tid & 63, quad = l >> 4, lr = l & 15;
    const int m0 = blockIdx.x * 64 + (w & 1) * 32;
    const int n0 = blockIdx.y * 64 + (w >> 1) * 32;
    f4 acc[2][2] = {};
    #pragma unroll
    for (int kc = 0; kc < KZ; kc += 32) {
        sh8 a[2], b[2];
        #pragma unroll
        for (int i = 0; i < 2; ++i)
            a[i] = *(const sh8*)&A[(size_t)(m0 + i * 16 + lr) * KZ + kc + quad * 8];
        #pragma unroll
        for (int j = 0; j < 2; ++j)
            b[j] = *(const sh8*)&W[(size_t)(n0 + j * 16 + lr) * KZ + kc + quad * 8];
        #pragma unroll
        for (int i = 0; i < 2; ++i)
            #pragma unroll
            for (int j = 0; j < 2; ++j)
                acc[i][j] = __builtin_amdgcn_mfma_f32_16x16x32_bf16(a[i], b[j], acc[i][j], 0, 0, 0);
    }
    #pragma unroll
    for (int i = 0; i < 2; ++i)
        #pragma unroll
        for (int j = 0; j < 2; ++j)
            #pragma unroll
            for (int r = 0; r < 4; ++r) {
                int row = m0 + i * 16 + quad * 4 + r;
                int col = n0 + j * 16 + lr;
                float v = acc[i][j][r] + bias[col];
                z[(size_t)row * CAT + col] = f2bf(fmaxf(v, 0.f));
            }
}

// ---------------------------------------------------------------------------
// Split-K partials of z @ Wout.T  M=512,N=320,K=2816/8. tile 64x64, waves 32x32.
// ---------------------------------------------------------------------------
__global__ __launch_bounds__(256) void k_out_part(
    const ushort_t* __restrict__ Z, const ushort_t* __restrict__ Wout,
    float* __restrict__ part)
{
    const int tid = threadIdx.x;
    const int w = tid >> 6, l = tid & 63, quad = l >> 4, lr = l & 15;
    const int m0 = blockIdx.x * 64 + (w & 1) * 32;
    const int n0 = blockIdx.y * 64 + (w >> 1) * 32;
    const int k0 = blockIdx.z * KCH;
    f4 acc[2][2] = {};
    for (int kc = k0; kc < k0 + KCH; kc += 32) {
        sh8 a[2], b[2];
        #pragma unroll
        for (int i = 0; i < 2; ++i)
            a[i] = *(const sh8*)&Z[(size_t)(m0 + i * 16 + lr) * CAT + kc + quad * 8];
        #pragma unroll
        for (int j = 0; j < 2; ++j)
            b[j] = *(const sh8*)&Wout[(size_t)(n0 + j * 16 + lr) * CAT + kc + quad * 8];
        #pragma unroll
        for (int i = 0; i < 2; ++i)
            #pragma unroll
            for (int j = 0; j < 2; ++j)
                acc[i][j] = __builtin_amdgcn_mfma_f32_16x16x32_bf16(a[i], b[j], acc[i][j], 0, 0, 0);
    }
    float* pbase = part + (size_t)blockIdx.z * BSZ * NOUTP;
    #pragma unroll
    for (int i = 0; i < 2; ++i)
        #pragma unroll
        for (int j = 0; j < 2; ++j)
            #pragma unroll
            for (int r = 0; r < 4; ++r) {
                int row = m0 + i * 16 + quad * 4 + r;
                int col = n0 + j * 16 + lr;
                pbase[(size_t)row * NOUTP + col] = acc[i][j][r];
            }
}

// ---------------------------------------------------------------------------
// Reduce split-K; relu+bf16 -> xh_nxt[.,0:256], sigmoid -> out
// ---------------------------------------------------------------------------
__global__ __launch_bounds__(256) void k_fin(
    const float* __restrict__ part, const float* __restrict__ b2,
    const float* __restrict__ bv, ushort_t* __restrict__ xh_nxt,
    float* __restrict__ out, int t)
{
    int idx = blockIdx.x * 256 + threadIdx.x;
    if (idx >= BSZ * NOUT) return;
    int b = idx / NOUT;
    int r = idx - b * NOUT;
    float sv = 0.f;
    #pragma unroll
    for (int s = 0; s < SPLITK; ++s)
        sv += part[((size_t)s * BSZ + b) * NOUTP + r];
    if (r < 256) {
        xh_nxt[(size_t)b * 512 + r] = f2bf(fmaxf(sv + b2[r], 0.f));
    } else {
        int n = r - 256;
        out[(size_t)b * (TT * NDD) + t * NDD + n] = sigf(sv + bv[n]);
    }
}

// ---------------------------------------------------------------------------
extern "C" void kernel_launch(void* const* d_in, const int* in_sizes, int n_in,
                              void* d_out, int out_size, void* d_ws, size_t ws_size,
                              hipStream_t stream)
{
    const float* desc = (const float*)d_in[0];
    const float* Wd   = (const float*)d_in[1];
    const float* bd   = (const float*)d_in[2];
    const float* W1   = (const float*)d_in[3];
    const float* b1   = (const float*)d_in[4];
    const float* W2   = (const float*)d_in[5];
    const float* b2   = (const float*)d_in[6];
    const float* Wv   = (const float*)d_in[7];
    const float* bv   = (const float*)d_in[8];
    const float* Wih  = (const float*)d_in[9];
    const float* Whh  = (const float*)d_in[10];
    const float* bih  = (const float*)d_in[11];
    const float* bhh  = (const float*)d_in[12];
    float* out = (float*)d_out;

    char* base = (char*)d_ws;
    size_t off = 0;
    auto alloc = [&](size_t bytes) -> char* {
        char* p = base + off;
        off = (off + bytes + 255) & ~(size_t)255;
        return p;
    };
    float*    c_    = (float*)alloc(BSZ * HID * 4);
    ushort_t* xhA   = (ushort_t*)alloc(BSZ * 512 * 2);
    ushort_t* xhB   = (ushort_t*)alloc(BSZ * 512 * 2);
    ushort_t* xz    = (ushort_t*)alloc(BSZ * KZ * 2);
    ushort_t* z     = (ushort_t*)alloc((size_t)BSZ * CAT * 2);
    ushort_t* Wzc   = (ushort_t*)alloc((size_t)CAT * KZ * 2);
    float*    bfold = (float*)alloc(CAT * 4);
    ushort_t* Wg    = (ushort_t*)alloc(1024 * 512 * 2);
    float*    bg    = (float*)alloc(1024 * 4);
    ushort_t* Wout  = (ushort_t*)alloc((size_t)NOUTP * CAT * 2);
    ushort_t* Dfold = (ushort_t*)alloc((size_t)TT * BSZ * 64 * 2);
    float*    part  = (float*)alloc((size_t)SPLITK * BSZ * NOUTP * 4);

    hipMemsetAsync(c_,  0, BSZ * HID * 4, stream);
    hipMemsetAsync(xhA, 0, BSZ * 512 * 2, stream);

    k_fold  <<<CAT, 64, 0, stream>>>(W1, Wd, bd, b1, Wzc, bfold);
    k_dfold <<<(TT * BSZ * 64) / 256, 256, 0, stream>>>(desc, Dfold);
    k_prep_g<<<(1024 * 512) / 256, 256, 0, stream>>>(Wih, Whh, bih, bhh, Wg, bg);
    k_prep_o<<<(NOUTP * CAT) / 256, 256, 0, stream>>>(W2, Wv, Wout);

    for (int t = 0; t < TT; ++t) {
        ushort_t* cur = (t & 1) ? xhB : xhA;
        ushort_t* nxt = (t & 1) ? xhA : xhB;
        k_gatecell<<<dim3(8, 16), 256, 0, stream>>>(
            cur, nxt, c_, xz, Dfold + (size_t)t * BSZ * 64, Wg, bg);
        k_gemm_z  <<<dim3(8, 44), 256, 0, stream>>>(xz, Wzc, bfold, z);
        k_out_part<<<dim3(8, 5, SPLITK), 256, 0, stream>>>(z, Wout, part);
        k_fin     <<<(BSZ * NOUT + 255) / 256, 256, 0, stream>>>(part, b2, bv, nxt, out, t);
    }
}